// Round 1
// baseline (67.299 us; speedup 1.0000x reference)
//
#include <hip/hip_runtime.h>

#define NAG 128   // num agents
#define TT  100   // timesteps
#define NC  5     // circles per vehicle

// Block layout: gridDim.x = TT * 64. Each block: t = blockIdx.x>>6,
// covers 256 of the 16384 (i,j) pairs for that t. 256 threads.
__global__ __launch_bounds__(256) void vehcoll_kernel(
    const float* __restrict__ traj,     // (NAG, TT, 4)
    const float* __restrict__ veh_att,  // (NAG, 2)
    const int*   __restrict__ ptr,      // (n_ptr,)
    float* __restrict__ out,            // TT*NAG*NAG penalties + 1 scalar
    int n_ptr)
{
    __shared__ float s_wcx[NAG][NC];
    __shared__ float s_wcy[NAG][NC];
    __shared__ float s_rad[NAG];
    __shared__ int   s_scene[NAG];

    const int t   = blockIdx.x >> 6;
    const int pb  = blockIdx.x & 63;
    const int tid = threadIdx.x;

    // ---- stage per-agent centers / radius / scene-id into LDS ----
    if (tid < NAG) {
        const int a = tid;
        // traj row-major (NAG, TT, 4): 16B-aligned float4
        float4 tr = *(const float4*)(traj + ((size_t)a * TT + t) * 4);
        float len = veh_att[a * 2 + 0];
        float wid = veh_att[a * 2 + 1];
        float rad  = 0.5f * wid;
        float cmin = -0.5f * len + rad;            // -half_len + rad
        float step = 0.25f * (len - wid);          // (cmax-cmin)/4, frac=linspace(0,1,5)
        float inv  = 1.0f / sqrtf(tr.z * tr.z + tr.w * tr.w);
        float hx = tr.z * inv, hy = tr.w * inv;
        #pragma unroll
        for (int c = 0; c < NC; ++c) {
            float cx = cmin + step * (float)c;
            s_wcx[a][c] = tr.x + cx * hx;
            s_wcy[a][c] = tr.y + cx * hy;
        }
        s_rad[a] = rad;
        // scene_id = searchsorted(ptr[1:], a, side='right')
        int sc = 0;
        for (int k = 1; k < n_ptr; ++k) sc += (ptr[k] <= a) ? 1 : 0;
        s_scene[a] = sc;
    }
    __syncthreads();

    // ---- one pair per thread ----
    const int p = pb * 256 + tid;       // pair index in [0, 16384)
    const int i = p >> 7;               // wave-uniform (i constant across 128 consecutive p)
    const int j = p & 127;

    float pen = 0.0f;
    if (i != j && s_scene[i] == s_scene[j]) {
        float ax[NC], ay[NC], bx[NC], by[NC];
        #pragma unroll
        for (int c = 0; c < NC; ++c) {
            ax[c] = s_wcx[i][c];  ay[c] = s_wcy[i][c];   // broadcast (i uniform in wave)
            bx[c] = s_wcx[j][c];  by[c] = s_wcy[j][c];
        }
        float minsq = 3.4e38f;
        #pragma unroll
        for (int ci = 0; ci < NC; ++ci) {
            #pragma unroll
            for (int cj = 0; cj < NC; ++cj) {
                float dx = ax[ci] - bx[cj];
                float dy = ay[ci] - by[cj];
                minsq = fminf(minsq, dx * dx + dy * dy);
            }
        }
        float d  = sqrtf(minsq);                 // min over dists == sqrt(min over sq)
        float pd = s_rad[i] + s_rad[j];          // BUFFER_DIST = 0
        if (d <= pd) pen = 1.0f - d / pd;
    }
    out[(size_t)t * NAG * NAG + p] = pen;

    // ---- num_pairs scalar (last element), once per launch ----
    if (blockIdx.x == 0 && tid == 0) {
        int np = 0;
        for (int k = 0; k + 1 < n_ptr; ++k) {
            int g = ptr[k + 1] - ptr[k];
            np += g * g - g;
        }
        out[(size_t)TT * NAG * NAG] = (float)np;
    }
}

extern "C" void kernel_launch(void* const* d_in, const int* in_sizes, int n_in,
                              void* d_out, int out_size, void* d_ws, size_t ws_size,
                              hipStream_t stream) {
    const float* traj    = (const float*)d_in[0];
    const float* veh_att = (const float*)d_in[1];
    const int*   ptr     = (const int*)d_in[2];
    float*       out     = (float*)d_out;
    const int n_ptr = in_sizes[2];

    dim3 grid(TT * 64);
    dim3 block(256);
    hipLaunchKernelGGL(vehcoll_kernel, grid, block, 0, stream,
                       traj, veh_att, ptr, out, n_ptr);
}

// Round 2
// 66.804 us; speedup vs baseline: 1.0074x; 1.0074x over previous
//
#include <hip/hip_runtime.h>

#define NAG 128   // num agents
#define TT  100   // timesteps
#define NC  5     // circles per vehicle
#define PB_PER_T 16              // pair-blocks per timestep
#define PAIRS_PER_BLOCK 1024     // 16384 / 16
#define PPT 4                    // pairs per thread (one float4 store)

// grid = TT*16 blocks of 256 threads; each thread computes 4 consecutive j's
// for one i and stores a float4. LDS is circle-major so per-j reads are
// independent scalars and the i-side is wave-broadcast.
__global__ __launch_bounds__(256) void vehcoll_kernel(
    const float* __restrict__ traj,     // (NAG, TT, 4)
    const float* __restrict__ veh_att,  // (NAG, 2)
    const int*   __restrict__ ptr,      // (n_ptr,)
    float* __restrict__ out,            // TT*NAG*NAG penalties + 1 scalar
    int n_ptr)
{
    __shared__ float s_cx[NC][NAG];
    __shared__ float s_cy[NC][NAG];
    __shared__ float s_rad[NAG];
    __shared__ int   s_scene[NAG];

    const int t   = blockIdx.x >> 4;
    const int pb  = blockIdx.x & 15;
    const int tid = threadIdx.x;

    // ---- stage per-agent circle centers / radius / scene-id into LDS ----
    if (tid < NAG) {
        const int a = tid;
        float4 tr = *(const float4*)(traj + ((size_t)a * TT + t) * 4);
        float len = veh_att[a * 2 + 0];
        float wid = veh_att[a * 2 + 1];
        float rad  = 0.5f * wid;
        float cmin = rad - 0.5f * len;             // -half_len + rad
        float step = 0.25f * (len - wid);          // (cmax-cmin)/4
        float inv  = 1.0f / sqrtf(tr.z * tr.z + tr.w * tr.w);
        float hx = tr.z * inv, hy = tr.w * inv;
        #pragma unroll
        for (int c = 0; c < NC; ++c) {
            float cx = cmin + step * (float)c;
            s_cx[c][a] = tr.x + cx * hx;
            s_cy[c][a] = tr.y + cx * hy;
        }
        s_rad[a] = rad;
        int sc = 0;                                // searchsorted(ptr[1:], a, 'right')
        for (int k = 1; k < n_ptr; ++k) sc += (ptr[k] <= a) ? 1 : 0;
        s_scene[a] = sc;
    }
    __syncthreads();

    // ---- 4 pairs per thread ----
    const int p0 = pb * PAIRS_PER_BLOCK + tid * PPT;  // 4-aligned
    const int i  = p0 >> 7;
    const int j0 = p0 & 127;

    float pen[PPT] = {0.f, 0.f, 0.f, 0.f};
    const int sci = s_scene[i];
    // scene ids are monotone in j: skip only if i's scene is strictly outside
    // the chunk's scene range (correct for arbitrary ptr).
    if (sci >= s_scene[j0] && sci <= s_scene[j0 + PPT - 1]) {
        float ix[NC], iy[NC];
        #pragma unroll
        for (int c = 0; c < NC; ++c) { ix[c] = s_cx[c][i]; iy[c] = s_cy[c][i]; }
        const float ri = s_rad[i];
        #pragma unroll
        for (int q = 0; q < PPT; ++q) {
            const int j = j0 + q;
            float minsq = 3.4e38f;
            #pragma unroll
            for (int ci = 0; ci < NC; ++ci) {
                const float jxc = 0.0f; (void)jxc;
                #pragma unroll
                for (int cj = 0; cj < NC; ++cj) {
                    float dx = ix[ci] - s_cx[cj][j];
                    float dy = iy[ci] - s_cy[cj][j];
                    minsq = fminf(minsq, dx * dx + dy * dy);
                }
            }
            float d  = sqrtf(minsq);               // min dist == sqrt(min sq)
            float pd = ri + s_rad[j];              // BUFFER_DIST = 0
            bool valid = (i != j) && (sci == s_scene[j]);
            pen[q] = (valid && d <= pd) ? 1.0f - d / pd : 0.0f;
        }
    }
    *(float4*)(out + (size_t)t * NAG * NAG + p0) =
        make_float4(pen[0], pen[1], pen[2], pen[3]);

    // ---- num_pairs scalar (last element) ----
    if (blockIdx.x == 0 && tid == 0) {
        int np = 0;
        for (int k = 0; k + 1 < n_ptr; ++k) {
            int g = ptr[k + 1] - ptr[k];
            np += g * g - g;
        }
        out[(size_t)TT * NAG * NAG] = (float)np;
    }
}

extern "C" void kernel_launch(void* const* d_in, const int* in_sizes, int n_in,
                              void* d_out, int out_size, void* d_ws, size_t ws_size,
                              hipStream_t stream) {
    const float* traj    = (const float*)d_in[0];
    const float* veh_att = (const float*)d_in[1];
    const int*   ptr     = (const int*)d_in[2];
    float*       out     = (float*)d_out;
    const int n_ptr = in_sizes[2];

    dim3 grid(TT * PB_PER_T);
    dim3 block(256);
    hipLaunchKernelGGL(vehcoll_kernel, grid, block, 0, stream,
                       traj, veh_att, ptr, out, n_ptr);
}